// Round 1
// baseline (240.294 us; speedup 1.0000x reference)
//
#include <hip/hip_runtime.h>
#include <hip/hip_bf16.h>
#include <cstdint>
#include <cstddef>

// Problem constants
#define BB   256   // batch
#define INU  8     // input unit
#define CCAP 1152  // input capsules
#define UU   10    // num_unit
#define OO   16    // unit size
#define UOv  160   // UU*OO
#define POSN 40960 // BB*UOv
#define NCH  48    // split-C chunks for s-pass
#define CPW  24    // capsules per chunk (CCAP/NCH)

typedef unsigned short ushort_t;
typedef unsigned int   uint_t;

__device__ __forceinline__ float bf_lo(uint_t x) { return __uint_as_float(x << 16); }
__device__ __forceinline__ float bf_hi(uint_t x) { return __uint_as_float(x & 0xffff0000u); }
__device__ __forceinline__ ushort_t f_to_bf(float f) {
  uint_t u = __float_as_uint(f);
  u += 0x7fffu + ((u >> 16) & 1u);   // round-to-nearest-even
  return (ushort_t)(u >> 16);
}

// ---------------- zero logits ----------------
__global__ void k_zero(float* __restrict__ p, int n) {
  int i = blockIdx.x * blockDim.x + threadIdx.x;
  if (i < n) p[i] = 0.f;
}

// ---------------- transpose x [2048][1152] -> xt [1152][2048] ----------------
// row j = b*8+i, so xt[c][b*8+i] = x[b][i][c]
__global__ void k_transpose(const float* __restrict__ x, float* __restrict__ xt) {
  __shared__ float tile[32][33];
  int c0 = blockIdx.x * 32;   // C dim
  int j0 = blockIdx.y * 32;   // B*IN dim
  int tx = threadIdx.x, ty = threadIdx.y;
#pragma unroll
  for (int r = 0; r < 32; r += 8)
    tile[ty + r][tx] = x[(size_t)(j0 + ty + r) * CCAP + c0 + tx];
  __syncthreads();
#pragma unroll
  for (int r = 0; r < 32; r += 8)
    xt[(size_t)(c0 + ty + r) * 2048 + j0 + tx] = tile[tx][ty + r];
}

// ---------------- u_hat generation: uh[c][b][uo] (bf16) ----------------
// block per c; 320 threads: bl = t/20 (16 b's per chunk), uo0 = t%20, j-loop covers uo0+20j
__global__ __launch_bounds__(320) void k_gen(const float* __restrict__ xt,
                                             const float* __restrict__ W,
                                             ushort_t* __restrict__ uh) {
  int c = blockIdx.x;
  __shared__ float Wl[UOv * 12];   // padded stride 12 (bank spread for float4 reads)
  __shared__ float xl[16 * INU];
  int t = threadIdx.x;
  for (int idx = t; idx < UOv * INU; idx += 320) {
    int uo = idx >> 3, i = idx & 7;
    Wl[uo * 12 + i] = W[(size_t)c * (UOv * INU) + idx];
  }
  int bl  = t / 20;
  int uo0 = t % 20;
  const float* xrow = xt + (size_t)c * 2048;
  for (int chunk = 0; chunk < 16; ++chunk) {
    __syncthreads();                       // protect xl (and order Wl on first iter)
    if (t < 128) xl[t] = xrow[chunk * 128 + t];
    __syncthreads();
    float4 xa = *(const float4*)&xl[bl * 8];
    float4 xb = *(const float4*)&xl[bl * 8 + 4];
    size_t obase = ((size_t)c * BB + chunk * 16 + bl) * UOv;
#pragma unroll
    for (int j = 0; j < 8; ++j) {
      int uo = uo0 + 20 * j;
      const float4 wa = *(const float4*)&Wl[uo * 12];
      const float4 wb = *(const float4*)&Wl[uo * 12 + 4];
      float a = xa.x * wa.x + xa.y * wa.y + xa.z * wa.z + xa.w * wa.w
              + xb.x * wb.x + xb.y * wb.y + xb.z * wb.z + xb.w * wb.w;
      uh[obase + uo] = f_to_bf(a);
    }
  }
}

// ---------------- softmax over u for each capsule c ----------------
__global__ void k_softmax(const float* __restrict__ logits, float* __restrict__ cw) {
  int c = blockIdx.x * blockDim.x + threadIdx.x;
  if (c >= CCAP) return;
  float l[UU];
  float mx = -1e30f;
#pragma unroll
  for (int k = 0; k < UU; ++k) { l[k] = logits[c * UU + k]; mx = fmaxf(mx, l[k]); }
  float sum = 0.f;
#pragma unroll
  for (int k = 0; k < UU; ++k) { l[k] = __expf(l[k] - mx); sum += l[k]; }
  float inv = 1.f / sum;
#pragma unroll
  for (int k = 0; k < UU; ++k) cw[c * UU + k] = l[k] * inv;
}

// ---------------- s-pass stage 1: partial[ch][pos] = sum over chunk c's ----------------
__global__ __launch_bounds__(256) void k_s1(const ushort_t* __restrict__ uh,
                                            const float* __restrict__ cw,
                                            float* __restrict__ part) {
  __shared__ float cwl[CPW * UU];
  int ch = blockIdx.y;
  int c0 = ch * CPW;
  int t = threadIdx.x;
  if (t < CPW * UU) cwl[t] = cw[c0 * UU + t];
  __syncthreads();
  int pos0 = (blockIdx.x * 256 + t) * 8;
  int m = pos0 % UOv;           // 8-span never crosses the 160 boundary (160%8==0)
  int uarr[8];
#pragma unroll
  for (int j = 0; j < 8; ++j) uarr[j] = (m + j) >> 4;
  float acc[8] = {0.f, 0.f, 0.f, 0.f, 0.f, 0.f, 0.f, 0.f};
#pragma unroll 4
  for (int ci = 0; ci < CPW; ++ci) {
    const uint4 raw = *(const uint4*)(uh + (size_t)(c0 + ci) * POSN + pos0);
    const float* cr = &cwl[ci * UU];
    acc[0] += cr[uarr[0]] * bf_lo(raw.x);
    acc[1] += cr[uarr[1]] * bf_hi(raw.x);
    acc[2] += cr[uarr[2]] * bf_lo(raw.y);
    acc[3] += cr[uarr[3]] * bf_hi(raw.y);
    acc[4] += cr[uarr[4]] * bf_lo(raw.z);
    acc[5] += cr[uarr[5]] * bf_hi(raw.z);
    acc[6] += cr[uarr[6]] * bf_lo(raw.w);
    acc[7] += cr[uarr[7]] * bf_hi(raw.w);
  }
  float4 o0 = make_float4(acc[0], acc[1], acc[2], acc[3]);
  float4 o1 = make_float4(acc[4], acc[5], acc[6], acc[7]);
  *(float4*)(part + (size_t)ch * POSN + pos0) = o0;
  *(float4*)(part + (size_t)ch * POSN + pos0 + 4) = o1;
}

// ---------------- s-pass stage 2 + squash -> v[b][uo] ----------------
__global__ void k_s2(const float* __restrict__ part, float* __restrict__ vout) {
  int b = blockIdx.x;
  int uo = threadIdx.x;  // 0..159
  float s = 0.f;
#pragma unroll 8
  for (int ch = 0; ch < NCH; ++ch) s += part[(size_t)ch * POSN + b * UOv + uo];
  float n2 = s * s;
#pragma unroll
  for (int off = 1; off < 16; off <<= 1) n2 += __shfl_xor(n2, off);  // reduce within u-group of 16
  float scale = n2 / ((1.f + n2) * sqrtf(n2));
  vout[b * UOv + uo] = s * scale;
}

// ---------------- agreement + logit update ----------------
// block per c, thread t owns batch row b=t. u = it>>1 is compile-time (static acc index).
__global__ __launch_bounds__(256) void k_agr(const ushort_t* __restrict__ uh,
                                             const float* __restrict__ v,
                                             float* __restrict__ logits) {
  int c = blockIdx.x;
  int t = threadIdx.x;  // = b
  const ushort_t* up = uh + (size_t)c * POSN + t * UOv;
  const float* vp = v + t * UOv;
  float acc[UU] = {0.f, 0.f, 0.f, 0.f, 0.f, 0.f, 0.f, 0.f, 0.f, 0.f};
#pragma unroll
  for (int it = 0; it < 20; ++it) {
    const uint4 raw = *(const uint4*)(up + it * 8);
    const float4 va = *(const float4*)(vp + it * 8);
    const float4 vb = *(const float4*)(vp + it * 8 + 4);
    acc[it >> 1] += bf_lo(raw.x) * va.x + bf_hi(raw.x) * va.y
                  + bf_lo(raw.y) * va.z + bf_hi(raw.y) * va.w
                  + bf_lo(raw.z) * vb.x + bf_hi(raw.z) * vb.y
                  + bf_lo(raw.w) * vb.z + bf_hi(raw.w) * vb.w;
  }
  __shared__ float red[4][UU];
  int lane = t & 63, wv = t >> 6;
#pragma unroll
  for (int u = 0; u < UU; ++u) {
    float a = acc[u];
    a += __shfl_xor(a, 1);
    a += __shfl_xor(a, 2);
    a += __shfl_xor(a, 4);
    a += __shfl_xor(a, 8);
    a += __shfl_xor(a, 16);
    a += __shfl_xor(a, 32);
    if (lane == 0) red[wv][u] = a;
  }
  __syncthreads();
  if (t < UU) {
    float sfin = red[0][t] + red[1][t] + red[2][t] + red[3][t];
    logits[c * UU + t] += sfin * (1.f / 256.f);
  }
}

extern "C" void kernel_launch(void* const* d_in, const int* in_sizes, int n_in,
                              void* d_out, int out_size, void* d_ws, size_t ws_size,
                              hipStream_t stream) {
  const float* x = (const float*)d_in[0];
  const float* W = (const float*)d_in[1];
  float* out = (float*)d_out;
  char* ws = (char*)d_ws;

  const size_t off_xt   = 0;                          // 1152*2048*4   = 9,437,184
  const size_t off_uh   = off_xt + 9437184;           // 47,185,920*2  = 94,371,840
  const size_t off_part = off_uh + 94371840;          // 48*40960*4    = 7,864,320
  const size_t off_cw   = off_part + 7864320;         // 11520*4
  const size_t off_lg   = off_cw + 46080;             // 11520*4
  const size_t off_v    = off_lg + 46080;             // 40960*4
  const size_t need     = off_v + 163840;             // ~112 MB total
  if (ws_size < need) return;  // graceful fail: output stays poisoned -> visible in bench

  float*    xt   = (float*)(ws + off_xt);
  ushort_t* uh   = (ushort_t*)(ws + off_uh);
  float*    part = (float*)(ws + off_part);
  float*    cw   = (float*)(ws + off_cw);
  float*    lg   = (float*)(ws + off_lg);
  float*    v    = (float*)(ws + off_v);

  k_zero<<<dim3((CCAP * UU + 255) / 256), dim3(256), 0, stream>>>(lg, CCAP * UU);
  k_transpose<<<dim3(36, 64), dim3(32, 8), 0, stream>>>(x, xt);
  k_gen<<<dim3(CCAP), dim3(320), 0, stream>>>(xt, W, uh);

  for (int it = 0; it < 4; ++it) {
    k_softmax<<<dim3(5), dim3(256), 0, stream>>>(lg, cw);
    k_s1<<<dim3(20, NCH), dim3(256), 0, stream>>>(uh, cw, part);
    float* vt = (it == 3) ? out : v;
    k_s2<<<dim3(BB), dim3(UOv), 0, stream>>>(part, vt);
    if (it < 3) k_agr<<<dim3(CCAP), dim3(256), 0, stream>>>(uh, v, lg);
  }
}

// Round 2
// 219.175 us; speedup vs baseline: 1.0964x; 1.0964x over previous
//
#include <hip/hip_runtime.h>
#include <cstdint>
#include <cstddef>

#define BB   256    // batch
#define INU  8      // input units
#define CCAP 1152   // input capsules
#define KK   9216   // INU*CCAP (GEMM1 reduction dim)
#define UU   10
#define OO   16
#define NN   160    // UU*OO
#define POSN 40960  // BB*NN
#define NSPLIT1 72  // GEMM1 split-K count
#define KC1  128    // KK/NSPLIT1 (divides CCAP: 1152 = 9*128 -> c contiguous per chunk)

// ---------- build Wt[k][n] = W[c][u][o][i], k = i*1152+c, n = u*16+o ----------
__global__ void k_wt(const float* __restrict__ W, float* __restrict__ wt) {
  int idx = blockIdx.x * 256 + threadIdx.x;
  if (idx >= KK * NN) return;
  int k = idx / NN, n = idx - k * NN;
  int i = k / CCAP, c = k - i * CCAP;
  int u = n >> 4, o = n & 15;
  wt[idx] = W[((size_t)(c * UU + u) * OO + o) * INU + i];
}

// ---------- transpose x[256][9216] -> xkb[9216][256] ----------
__global__ void k_xkb(const float* __restrict__ x, float* __restrict__ xkb) {
  __shared__ float tile[32][33];
  int k0 = blockIdx.x * 32, b0 = blockIdx.y * 32;
  int tx = threadIdx.x, ty = threadIdx.y;
#pragma unroll
  for (int r = 0; r < 32; r += 8)
    tile[ty + r][tx] = x[(size_t)(b0 + ty + r) * KK + k0 + tx];
  __syncthreads();
#pragma unroll
  for (int r = 0; r < 32; r += 8)
    xkb[(size_t)(k0 + ty + r) * BB + b0 + tx] = tile[tx][ty + r];
}

// ---------- init cw = 0.1 (softmax of zero logits), lg = 0 ----------
__global__ void k_fill(float* __restrict__ cw, float* __restrict__ lg) {
  int i = blockIdx.x * 256 + threadIdx.x;
  if (i < CCAP * UU) { cw[i] = 0.1f; lg[i] = 0.f; }
}

// ---------- GEMM1: part[sp][b][n] = sum_{k in chunk} x[b,k] * cw[c(k),u(n)] * wt[k,n] ----------
// grid (8, 72), block 256. BM=32, BN=160(full), KC=128 (4 k-tiles of 32).
__global__ __launch_bounds__(256) void k_gemm1(const float* __restrict__ x,
                                               const float* __restrict__ wt,
                                               const float* __restrict__ cw,
                                               float* __restrict__ part) {
  __shared__ float As[32][33];
  __shared__ float Bs[32 * NN];
  __shared__ float cwl[KC1 * UU];  // cw slice for this chunk's contiguous c-range
  int m0 = blockIdx.x * 32;
  int sp = blockIdx.y;
  int tid = threadIdx.x;
  int cbase10 = (sp % 9) * KC1 * UU;
  for (int idx = tid; idx < KC1 * UU; idx += 256) cwl[idx] = cw[cbase10 + idx];
  int r = tid >> 3;        // row 0..31 (shared by load & compute roles)
  int g = tid & 7;         // col-group 0..7
  int nb = g * 20;         // this thread's 20-column base
  int utab[20];
#pragma unroll
  for (int m = 0; m < 20; ++m) utab[m] = (nb + m) >> 4;
  float4 acc[5] = {};
  for (int t = 0; t < 4; ++t) {
    int k0 = sp * KC1 + t * 32;
    __syncthreads();  // LDS write-after-read; also orders cwl on first iter
    {  // stage A tile [32 rows b][32 k]
      float4 a4 = *(const float4*)&x[(size_t)(m0 + r) * KK + k0 + (g << 2)];
      As[r][(g << 2) + 0] = a4.x; As[r][(g << 2) + 1] = a4.y;
      As[r][(g << 2) + 2] = a4.z; As[r][(g << 2) + 3] = a4.w;
    }
    {  // stage B tile [32 k][160 n] with cw scale folded in
      int cl10 = (t * 32 + r) * UU;
      const float* wrow = &wt[(size_t)(k0 + r) * NN + nb];
      float* brow = &Bs[r * NN + nb];
#pragma unroll
      for (int j = 0; j < 5; ++j) {
        float4 w4 = *(const float4*)&wrow[4 * j];
        w4.x *= cwl[cl10 + utab[4 * j + 0]];
        w4.y *= cwl[cl10 + utab[4 * j + 1]];
        w4.z *= cwl[cl10 + utab[4 * j + 2]];
        w4.w *= cwl[cl10 + utab[4 * j + 3]];
        *(float4*)&brow[4 * j] = w4;
      }
    }
    __syncthreads();
#pragma unroll
    for (int k = 0; k < 32; ++k) {
      float a = As[r][k];
      const float* bk = &Bs[k * NN + nb];
#pragma unroll
      for (int j = 0; j < 5; ++j) {
        float4 b4 = *(const float4*)&bk[4 * j];
        acc[j].x += a * b4.x; acc[j].y += a * b4.y;
        acc[j].z += a * b4.z; acc[j].w += a * b4.w;
      }
    }
  }
  float* prow = &part[(size_t)sp * POSN + (size_t)(m0 + r) * NN + nb];
#pragma unroll
  for (int j = 0; j < 5; ++j) *(float4*)&prow[4 * j] = acc[j];
}

// ---------- reduce split-K partials + squash -> v (or out) ----------
__global__ void k_reduce(const float* __restrict__ part, float* __restrict__ vout) {
  int b = blockIdx.x, uo = threadIdx.x;  // 256 blocks x 160 threads
  float s = 0.f;
  for (int sp = 0; sp < NSPLIT1; ++sp) s += part[(size_t)sp * POSN + b * NN + uo];
  float n2 = s * s;
#pragma unroll
  for (int off = 1; off < 16; off <<= 1) n2 += __shfl_xor(n2, off);  // sum over o (16-groups)
  float scale = n2 / ((1.f + n2) * sqrtf(n2));
  vout[b * NN + uo] = s * scale;
}

// ---------- GEMM2 + agreement epilogue ----------
// T[k][n] = sum_b xkb[k][b]*v[b][n]; agp[sp][k][u] = sum_o wt[k][n]*T[k][n]
// grid (288, 2), block 256. BM=32 rows of k, split-K over b (2 x 128).
__global__ __launch_bounds__(256) void k_gemm2(const float* __restrict__ xkb,
                                               const float* __restrict__ v,
                                               const float* __restrict__ wt,
                                               float* __restrict__ agp) {
  __shared__ float As[32][33];
  __shared__ float Bs[32 * NN];
  __shared__ float Tl[32][168];  // padded for the o-reduce phase
  int m0 = blockIdx.x * 32;
  int sp = blockIdx.y;
  int tid = threadIdx.x;
  int r = tid >> 3, g = tid & 7;
  int nb = g * 20;
  float4 acc[5] = {};
  for (int t = 0; t < 4; ++t) {
    int kb0 = sp * 128 + t * 32;
    __syncthreads();
    {  // stage A tile [32 k-rows][32 b]
      float4 a4 = *(const float4*)&xkb[(size_t)(m0 + r) * BB + kb0 + (g << 2)];
      As[r][(g << 2) + 0] = a4.x; As[r][(g << 2) + 1] = a4.y;
      As[r][(g << 2) + 2] = a4.z; As[r][(g << 2) + 3] = a4.w;
    }
    {  // stage B tile [32 b][160 n] from v
      const float* vrow = &v[(size_t)(kb0 + r) * NN + nb];
      float* brow = &Bs[r * NN + nb];
#pragma unroll
      for (int j = 0; j < 5; ++j) *(float4*)&brow[4 * j] = *(const float4*)&vrow[4 * j];
    }
    __syncthreads();
#pragma unroll
    for (int k = 0; k < 32; ++k) {
      float a = As[r][k];
      const float* bk = &Bs[k * NN + nb];
#pragma unroll
      for (int j = 0; j < 5; ++j) {
        float4 b4 = *(const float4*)&bk[4 * j];
        acc[j].x += a * b4.x; acc[j].y += a * b4.y;
        acc[j].z += a * b4.z; acc[j].w += a * b4.w;
      }
    }
  }
  // epilogue: elementwise * Wt, stage to LDS
  {
    const float* wrow = &wt[(size_t)(m0 + r) * NN + nb];
#pragma unroll
    for (int j = 0; j < 5; ++j) {
      float4 w4 = *(const float4*)&wrow[4 * j];
      float4 p;
      p.x = acc[j].x * w4.x; p.y = acc[j].y * w4.y;
      p.z = acc[j].z * w4.z; p.w = acc[j].w * w4.w;
      *(float4*)&Tl[r][nb + 4 * j] = p;
    }
  }
  __syncthreads();
  // reduce over o per (k-row, u): 320 outputs
  for (int idx = tid; idx < 32 * UU; idx += 256) {
    int krow = idx / UU, u = idx - krow * UU;
    float s = 0.f;
#pragma unroll
    for (int o = 0; o < OO; ++o) s += Tl[krow][u * OO + o];
    agp[(size_t)sp * (KK * UU) + (size_t)m0 * UU + idx] = s;
  }
}

// ---------- finish: agp -> ag -> logits += ag/B -> softmax -> cw ----------
__global__ void k_finish(const float* __restrict__ agp, float* __restrict__ lg,
                         float* __restrict__ cw) {
  int c = blockIdx.x * 256 + threadIdx.x;
  if (c >= CCAP) return;
  float su[UU] = {};
#pragma unroll
  for (int sp = 0; sp < 2; ++sp)
#pragma unroll
    for (int i = 0; i < INU; ++i) {
      const float* row = &agp[(size_t)sp * (KK * UU) + (size_t)(i * CCAP + c) * UU];
#pragma unroll
      for (int u = 0; u < UU; ++u) su[u] += row[u];
    }
  float l[UU];
  float mx = -1e30f;
#pragma unroll
  for (int u = 0; u < UU; ++u) {
    float nl = lg[c * UU + u] + su[u] * (1.f / 256.f);
    lg[c * UU + u] = nl;
    l[u] = nl;
    mx = fmaxf(mx, nl);
  }
  float sum = 0.f;
#pragma unroll
  for (int u = 0; u < UU; ++u) { l[u] = __expf(l[u] - mx); sum += l[u]; }
  float inv = 1.f / sum;
#pragma unroll
  for (int u = 0; u < UU; ++u) cw[c * UU + u] = l[u] * inv;
}

extern "C" void kernel_launch(void* const* d_in, const int* in_sizes, int n_in,
                              void* d_out, int out_size, void* d_ws, size_t ws_size,
                              hipStream_t stream) {
  const float* x = (const float*)d_in[0];
  const float* W = (const float*)d_in[1];
  float* out = (float*)d_out;
  char* ws = (char*)d_ws;

  const size_t off_wt   = 0;                       // 9216*160*4   = 5,898,240
  const size_t off_xkb  = off_wt + 5898240;        // 9216*256*4   = 9,437,184
  const size_t off_part = off_xkb + 9437184;       // 72*40960*4   = 11,796,480
  const size_t off_cw   = off_part + 11796480;     // 11520*4
  const size_t off_lg   = off_cw + 46080;
  const size_t off_v    = off_lg + 46080;          // 40960*4
  const size_t off_agp  = off_v + 163840;          // 2*92160*4    = 737,280
  const size_t need     = off_agp + 737280;        // ~28.1 MB
  if (ws_size < need) return;  // output stays poisoned -> visible failure

  float* wt   = (float*)(ws + off_wt);
  float* xkb  = (float*)(ws + off_xkb);
  float* part = (float*)(ws + off_part);
  float* cw   = (float*)(ws + off_cw);
  float* lg   = (float*)(ws + off_lg);
  float* v    = (float*)(ws + off_v);
  float* agp  = (float*)(ws + off_agp);

  k_wt  <<<dim3((KK * NN + 255) / 256), dim3(256), 0, stream>>>(W, wt);
  k_xkb <<<dim3(KK / 32, BB / 32), dim3(32, 8), 0, stream>>>(x, xkb);
  k_fill<<<dim3((CCAP * UU + 255) / 256), dim3(256), 0, stream>>>(cw, lg);

  for (int it = 0; it < 4; ++it) {
    k_gemm1 <<<dim3(BB / 32, NSPLIT1), dim3(256), 0, stream>>>(x, wt, cw, part);
    k_reduce<<<dim3(BB), dim3(NN), 0, stream>>>(part, (it == 3) ? out : v);
    if (it < 3) {
      k_gemm2 <<<dim3(KK / 32, 2), dim3(256), 0, stream>>>(xkb, v, wt, agp);
      k_finish<<<dim3((CCAP + 255) / 256), dim3(256), 0, stream>>>(agp, lg, cw);
    }
  }
}

// Round 3
// 158.897 us; speedup vs baseline: 1.5123x; 1.3794x over previous
//
#include <hip/hip_runtime.h>
#include <cstdint>
#include <cstddef>

#define BB 256
#define CCAP 1152
#define KK 9216       // INU*CCAP, k = i*1152 + c
#define UU 10
#define NN 160
#define KSPLIT 48
#define KTL 6         // k-tiles (of 32) per split; 48*6 = 288
#define POSN 40960

typedef __attribute__((ext_vector_type(8))) short bf16x8;
typedef __attribute__((ext_vector_type(4))) float f32x4;
typedef unsigned int uint_t;
typedef unsigned short ushort_t;

__device__ __forceinline__ ushort_t f2bf(float f) {
  uint_t u = __float_as_uint(f);
  u += 0x7fffu + ((u >> 16) & 1u);   // RNE
  return (ushort_t)(u >> 16);
}
__device__ __forceinline__ float bf2f(ushort_t h) {
  return __uint_as_float(((uint_t)h) << 16);
}

// ---------------- prep: W fragment packs + cw/lg init ----------------
// w1[(kt*10+nt)*64+l][8 bf16]: B-frag layout, B[k][n]=W[c][u=nt][o=l&15][i], k=kt*32+8*(l>>4)+j
// wd[(mt2*10+nt)*64+l][4 f32]: D-layout W for gemm2 epilogue, krow=mt2*16+4*(l>>4)+r
__global__ void k_prep(const float* __restrict__ W, ushort_t* __restrict__ w1,
                       float* __restrict__ wd, float* __restrict__ cw,
                       float* __restrict__ lg) {
  int gid = blockIdx.x * 256 + threadIdx.x;
  if (gid < 184320) {                       // 288*10*64 w1 frag-lanes
    int l = gid & 63, tile = gid >> 6;
    int nt = tile % 10, kt = tile / 10;
    int lm = l & 15, lgp = l >> 4;
    ushort_t o[8];
#pragma unroll
    for (int j = 0; j < 8; ++j) {
      int k = kt * 32 + lgp * 8 + j;
      int i = k / CCAP, c = k - i * CCAP;
      o[j] = f2bf(W[((size_t)(c * UU + nt) * 16 + lm) * 8 + i]);
    }
    uint4 pk;
    pk.x = (uint_t)o[0] | ((uint_t)o[1] << 16);
    pk.y = (uint_t)o[2] | ((uint_t)o[3] << 16);
    pk.z = (uint_t)o[4] | ((uint_t)o[5] << 16);
    pk.w = (uint_t)o[6] | ((uint_t)o[7] << 16);
    *(uint4*)(w1 + (size_t)gid * 8) = pk;
  } else if (gid < 552960) {                // 576*10*64 wd frag-lanes
    int g2 = gid - 184320;
    int l = g2 & 63, tile = g2 >> 6;
    int nt = tile % 10, mt2 = tile / 10;
    int lm = l & 15, lgp = l >> 4;
    float vv[4];
#pragma unroll
    for (int r = 0; r < 4; ++r) {
      int krow = mt2 * 16 + lgp * 4 + r;
      int i = krow / CCAP, c = krow - i * CCAP;
      vv[r] = W[((size_t)(c * UU + nt) * 16 + lm) * 8 + i];
    }
    *(float4*)(wd + (size_t)g2 * 4) = make_float4(vv[0], vv[1], vv[2], vv[3]);
  } else if (gid < 564480) {                // cw = softmax(0) = 0.1, lg = 0
    int g3 = gid - 552960;
    cw[g3] = 0.1f;
    lg[g3] = 0.f;
  }
}

// ---------------- transpose x[256][9216] -> xkb[9216][256] ----------------
__global__ void k_xkb(const float* __restrict__ x, float* __restrict__ xkb) {
  __shared__ float tile[32][33];
  int k0 = blockIdx.x * 32, b0 = blockIdx.y * 32;
  int tx = threadIdx.x, ty = threadIdx.y;
#pragma unroll
  for (int r = 0; r < 32; r += 8)
    tile[ty + r][tx] = x[(size_t)(b0 + ty + r) * KK + k0 + tx];
  __syncthreads();
#pragma unroll
  for (int r = 0; r < 32; r += 8)
    xkb[(size_t)(k0 + ty + r) * BB + b0 + tx] = tile[tx][ty + r];
}

// ---------------- GEMM1 (MFMA): part[sp] += x * (cw .* wt) ----------------
// grid (5 ntp, 48 sp), 256 thr = 4 waves; wave-tile 64 rows x 32 cols; K-chunk 192.
__global__ __launch_bounds__(256) void k_gemm1(const float* __restrict__ x,
                                               const ushort_t* __restrict__ w1,
                                               const float* __restrict__ cw,
                                               float* __restrict__ part) {
  int ntp = blockIdx.x;
  int sp  = blockIdx.y;
  int tid = threadIdx.x;
  int wv = tid >> 6, l = tid & 63;
  int lm = l & 15, lgp = l >> 4;
  __shared__ float cwl[192][2];
  int c0 = (sp * 192) % CCAP;    // contiguous c-range (192 | 1152, no wrap)
  for (int idx = tid; idx < 192; idx += 256) {
    cwl[idx][0] = cw[(c0 + idx) * UU + ntp * 2];
    cwl[idx][1] = cw[(c0 + idx) * UU + ntp * 2 + 1];
  }
  __syncthreads();
  f32x4 z = {0.f, 0.f, 0.f, 0.f};
  f32x4 acc[4][2];
#pragma unroll
  for (int q = 0; q < 4; ++q) { acc[q][0] = z; acc[q][1] = z; }
  for (int ktl = 0; ktl < KTL; ++ktl) {
    int kt = sp * KTL + ktl;
    bf16x8 af[4];
#pragma unroll
    for (int q = 0; q < 4; ++q) {
      const float* ap = x + (size_t)(wv * 64 + q * 16 + lm) * KK + kt * 32 + lgp * 8;
      float4 a0 = *(const float4*)ap;
      float4 a1 = *(const float4*)(ap + 4);
      bf16x8 t;
      t[0] = (short)f2bf(a0.x); t[1] = (short)f2bf(a0.y);
      t[2] = (short)f2bf(a0.z); t[3] = (short)f2bf(a0.w);
      t[4] = (short)f2bf(a1.x); t[5] = (short)f2bf(a1.y);
      t[6] = (short)f2bf(a1.z); t[7] = (short)f2bf(a1.w);
      af[q] = t;
    }
    bf16x8 bfr[2];
    int cl = ktl * 32 + lgp * 8;
#pragma unroll
    for (int nb = 0; nb < 2; ++nb) {
      const ushort_t* wp = w1 + ((size_t)kt * UU + ntp * 2 + nb) * 512 + (size_t)l * 8;
      uint4 raw = *(const uint4*)wp;
      bf16x8 t;
      t[0] = (short)f2bf(bf2f((ushort_t)(raw.x & 0xffff)) * cwl[cl + 0][nb]);
      t[1] = (short)f2bf(bf2f((ushort_t)(raw.x >> 16))    * cwl[cl + 1][nb]);
      t[2] = (short)f2bf(bf2f((ushort_t)(raw.y & 0xffff)) * cwl[cl + 2][nb]);
      t[3] = (short)f2bf(bf2f((ushort_t)(raw.y >> 16))    * cwl[cl + 3][nb]);
      t[4] = (short)f2bf(bf2f((ushort_t)(raw.z & 0xffff)) * cwl[cl + 4][nb]);
      t[5] = (short)f2bf(bf2f((ushort_t)(raw.z >> 16))    * cwl[cl + 5][nb]);
      t[6] = (short)f2bf(bf2f((ushort_t)(raw.w & 0xffff)) * cwl[cl + 6][nb]);
      t[7] = (short)f2bf(bf2f((ushort_t)(raw.w >> 16))    * cwl[cl + 7][nb]);
      bfr[nb] = t;
    }
#pragma unroll
    for (int q = 0; q < 4; ++q)
#pragma unroll
      for (int nb = 0; nb < 2; ++nb)
        acc[q][nb] = __builtin_amdgcn_mfma_f32_16x16x32_bf16(af[q], bfr[nb], acc[q][nb], 0, 0, 0);
  }
  float* pb = part + (size_t)sp * POSN;
#pragma unroll
  for (int q = 0; q < 4; ++q)
#pragma unroll
    for (int nb = 0; nb < 2; ++nb)
#pragma unroll
      for (int r = 0; r < 4; ++r)
        pb[(size_t)(wv * 64 + q * 16 + lgp * 4 + r) * NN + ntp * 32 + nb * 16 + lm] = acc[q][nb][r];
}

// ---------------- reduce split-K + squash -> v/out; also zero ag ----------------
__global__ void k_reduce(const float* __restrict__ part, float* __restrict__ vout,
                         float* __restrict__ ag) {
  int b = blockIdx.x, uo = threadIdx.x;   // 256 x 160
  if (b < 72) ag[b * NN + uo] = 0.f;      // 72*160 = 11520 = CCAP*UU
  float s = 0.f;
  for (int sp = 0; sp < KSPLIT; ++sp) s += part[(size_t)sp * POSN + b * NN + uo];
  float n2 = s * s;
#pragma unroll
  for (int off = 1; off < 16; off <<= 1) n2 += __shfl_xor(n2, off);
  float scale = n2 / ((1.f + n2) * sqrtf(n2));
  vout[b * NN + uo] = s * scale;
}

// ---------------- GEMM2 (MFMA) + agreement epilogue -> atomic ag ----------------
// T[k][n] = sum_b xkb[k][b]*v[b][n]; ag[c][u] += sum_o wt[k][n]*T[k][n]
// grid (36 mb, 5 ntp), 256 thr = 4 waves; block covers 256 k-rows, full b-reduction.
__global__ __launch_bounds__(256) void k_gemm2(const float* __restrict__ xkb,
                                               const float* __restrict__ v,
                                               const float* __restrict__ wd,
                                               float* __restrict__ ag) {
  int mb = blockIdx.x;
  int ntp = blockIdx.y;
  int tid = threadIdx.x;
  int wv = tid >> 6, l = tid & 63;
  int lm = l & 15, lgp = l >> 4;
  __shared__ float vsT[32][260];          // v-slice transposed, stride 260: aligned + uniform banks
  {
    const float* vp = v + (size_t)tid * NN + ntp * 32;
#pragma unroll
    for (int h = 0; h < 8; ++h) {
      float4 t = *(const float4*)(vp + h * 4);
      vsT[h * 4 + 0][tid] = t.x;
      vsT[h * 4 + 1][tid] = t.y;
      vsT[h * 4 + 2][tid] = t.z;
      vsT[h * 4 + 3][tid] = t.w;
    }
  }
  __syncthreads();
  bf16x8 bfr[8][2];                       // all B-frags built once per wave
#pragma unroll
  for (int bt = 0; bt < 8; ++bt)
#pragma unroll
    for (int nb = 0; nb < 2; ++nb) {
      const float* q = &vsT[nb * 16 + lm][bt * 32 + lgp * 8];
      float4 v0 = *(const float4*)q;
      float4 v1 = *(const float4*)(q + 4);
      bf16x8 t;
      t[0] = (short)f2bf(v0.x); t[1] = (short)f2bf(v0.y);
      t[2] = (short)f2bf(v0.z); t[3] = (short)f2bf(v0.w);
      t[4] = (short)f2bf(v1.x); t[5] = (short)f2bf(v1.y);
      t[6] = (short)f2bf(v1.z); t[7] = (short)f2bf(v1.w);
      bfr[bt][nb] = t;
    }
  f32x4 z = {0.f, 0.f, 0.f, 0.f};
  f32x4 acc[4][2];
#pragma unroll
  for (int q = 0; q < 4; ++q) { acc[q][0] = z; acc[q][1] = z; }
  for (int bt = 0; bt < 8; ++bt) {
    bf16x8 af[4];
#pragma unroll
    for (int q = 0; q < 4; ++q) {
      int mt2 = mb * 16 + wv * 4 + q;
      const float* ap = xkb + (size_t)(mt2 * 16 + lm) * BB + bt * 32 + lgp * 8;
      float4 a0 = *(const float4*)ap;
      float4 a1 = *(const float4*)(ap + 4);
      bf16x8 t;
      t[0] = (short)f2bf(a0.x); t[1] = (short)f2bf(a0.y);
      t[2] = (short)f2bf(a0.z); t[3] = (short)f2bf(a0.w);
      t[4] = (short)f2bf(a1.x); t[5] = (short)f2bf(a1.y);
      t[6] = (short)f2bf(a1.z); t[7] = (short)f2bf(a1.w);
      af[q] = t;
    }
#pragma unroll
    for (int q = 0; q < 4; ++q)
#pragma unroll
      for (int nb = 0; nb < 2; ++nb)
        acc[q][nb] = __builtin_amdgcn_mfma_f32_16x16x32_bf16(af[q], bfr[bt][nb], acc[q][nb], 0, 0, 0);
  }
  // epilogue: dot with W (D-layout pack), reduce over o (lm lanes), atomic into ag
#pragma unroll
  for (int q = 0; q < 4; ++q) {
    int mt2 = mb * 16 + wv * 4 + q;
#pragma unroll
    for (int nb = 0; nb < 2; ++nb) {
      int nt = ntp * 2 + nb;
      float4 wdv = *(const float4*)(wd + ((size_t)(mt2 * UU + nt) * 64 + l) * 4);
      float p0 = acc[q][nb][0] * wdv.x;
      float p1 = acc[q][nb][1] * wdv.y;
      float p2 = acc[q][nb][2] * wdv.z;
      float p3 = acc[q][nb][3] * wdv.w;
#pragma unroll
      for (int off = 1; off < 16; off <<= 1) {
        p0 += __shfl_xor(p0, off);
        p1 += __shfl_xor(p1, off);
        p2 += __shfl_xor(p2, off);
        p3 += __shfl_xor(p3, off);
      }
      if (lm == 0) {
        int krow = mt2 * 16 + lgp * 4;    // rows krow..krow+3, same i (16 | 1152)
        int c = krow % CCAP;
        atomicAdd(&ag[(c + 0) * UU + nt], p0);
        atomicAdd(&ag[(c + 1) * UU + nt], p1);
        atomicAdd(&ag[(c + 2) * UU + nt], p2);
        atomicAdd(&ag[(c + 3) * UU + nt], p3);
      }
    }
  }
}

// ---------------- finish: logits += ag/B, softmax -> cw ----------------
__global__ void k_finish(const float* __restrict__ ag, float* __restrict__ lg,
                         float* __restrict__ cw) {
  int c = blockIdx.x * 256 + threadIdx.x;
  if (c >= CCAP) return;
  float l[UU];
  float mx = -1e30f;
#pragma unroll
  for (int u = 0; u < UU; ++u) {
    float nl = lg[c * UU + u] + ag[c * UU + u] * (1.f / 256.f);
    lg[c * UU + u] = nl;
    l[u] = nl;
    mx = fmaxf(mx, nl);
  }
  float s = 0.f;
#pragma unroll
  for (int u = 0; u < UU; ++u) { l[u] = __expf(l[u] - mx); s += l[u]; }
  float inv = 1.f / s;
#pragma unroll
  for (int u = 0; u < UU; ++u) cw[c * UU + u] = l[u] * inv;
}

extern "C" void kernel_launch(void* const* d_in, const int* in_sizes, int n_in,
                              void* d_out, int out_size, void* d_ws, size_t ws_size,
                              hipStream_t stream) {
  const float* x = (const float*)d_in[0];
  const float* W = (const float*)d_in[1];
  float* out = (float*)d_out;
  char* ws = (char*)d_ws;

  const size_t off_w1   = 0;                     // 1,474,560 bf16 = 2,949,120 B
  const size_t off_wd   = off_w1 + 2949120;      // 1,474,560 f32  = 5,898,240 B
  const size_t off_xkb  = off_wd + 5898240;      // 9,437,184 B
  const size_t off_part = off_xkb + 9437184;     // 48*40960*4 = 7,864,320 B
  const size_t off_cw   = off_part + 7864320;    // 46,080 B
  const size_t off_lg   = off_cw + 46080;        // 46,080 B
  const size_t off_v    = off_lg + 46080;        // 163,840 B
  const size_t off_ag   = off_v + 163840;        // 46,080 B
  const size_t need     = off_ag + 46080;        // ~25.2 MB
  if (ws_size < need) return;  // output stays poisoned -> visible failure

  ushort_t* w1  = (ushort_t*)(ws + off_w1);
  float* wd     = (float*)(ws + off_wd);
  float* xkb    = (float*)(ws + off_xkb);
  float* part   = (float*)(ws + off_part);
  float* cw     = (float*)(ws + off_cw);
  float* lg     = (float*)(ws + off_lg);
  float* v      = (float*)(ws + off_v);
  float* ag     = (float*)(ws + off_ag);

  k_prep<<<dim3(2205), dim3(256), 0, stream>>>(W, w1, wd, cw, lg);
  k_xkb <<<dim3(KK / 32, BB / 32), dim3(32, 8), 0, stream>>>(x, xkb);

  for (int it = 0; it < 4; ++it) {
    k_gemm1 <<<dim3(5, KSPLIT), dim3(256), 0, stream>>>(x, w1, cw, part);
    k_reduce<<<dim3(BB), dim3(NN), 0, stream>>>(part, (it == 3) ? out : v, ag);
    if (it < 3) {
      k_gemm2 <<<dim3(36, 5), dim3(256), 0, stream>>>(xkb, v, wd, ag);
      k_finish<<<dim3(5), dim3(256), 0, stream>>>(ag, lg, cw);
    }
  }
}

// Round 4
// 150.424 us; speedup vs baseline: 1.5974x; 1.0563x over previous
//
#include <hip/hip_runtime.h>
#include <cstdint>
#include <cstddef>

#define BB 256
#define CCAP 1152
#define KK 9216       // INU*CCAP, k = i*1152 + c
#define UU 10
#define NN 160
#define KSPLIT 48
#define KTL 6         // k-tiles (of 32) per split; 48*6 = 288
#define POSN 40960

typedef __attribute__((ext_vector_type(8))) short bf16x8;
typedef __attribute__((ext_vector_type(4))) float f32x4;
typedef unsigned int uint_t;
typedef unsigned short ushort_t;

__device__ __forceinline__ ushort_t f2bf(float f) {
  uint_t u = __float_as_uint(f);
  u += 0x7fffu + ((u >> 16) & 1u);   // RNE
  return (ushort_t)(u >> 16);
}
__device__ __forceinline__ float bf2f(ushort_t h) {
  return __uint_as_float(((uint_t)h) << 16);
}

// ---------------- prep: W fragment packs (w1, w1s=0.1*w1), wd, lg=0 ----------------
// w1[(kt*10+nt)*64+l][8 bf16]: B-frag, B[k][n]=W[c][u=nt][o=l&15][i], k=kt*32+8*(l>>4)+j
// wd[(mt2*10+nt)*64+l][4 f32]: D-layout W for gemm2 epilogue, krow=mt2*16+4*(l>>4)+r
__global__ void k_prep(const float* __restrict__ W, ushort_t* __restrict__ w1,
                       ushort_t* __restrict__ w1s, float* __restrict__ wd,
                       float* __restrict__ lg) {
  int gid = blockIdx.x * 256 + threadIdx.x;
  if (gid < 184320) {                       // 288*10*64 w1 frag-lanes
    int l = gid & 63, tile = gid >> 6;
    int nt = tile % 10, kt = tile / 10;
    int lm = l & 15, lgp = l >> 4;
    ushort_t o[8], os[8];
#pragma unroll
    for (int j = 0; j < 8; ++j) {
      int k = kt * 32 + lgp * 8 + j;
      int i = k / CCAP, c = k - i * CCAP;
      float w = W[((size_t)(c * UU + nt) * 16 + lm) * 8 + i];
      o[j]  = f2bf(w);
      os[j] = f2bf(0.1f * bf2f(o[j]));      // iteration-0 cw = softmax(0) = 0.1
    }
    uint4 pk, pks;
    pk.x  = (uint_t)o[0]  | ((uint_t)o[1]  << 16);
    pk.y  = (uint_t)o[2]  | ((uint_t)o[3]  << 16);
    pk.z  = (uint_t)o[4]  | ((uint_t)o[5]  << 16);
    pk.w  = (uint_t)o[6]  | ((uint_t)o[7]  << 16);
    pks.x = (uint_t)os[0] | ((uint_t)os[1] << 16);
    pks.y = (uint_t)os[2] | ((uint_t)os[3] << 16);
    pks.z = (uint_t)os[4] | ((uint_t)os[5] << 16);
    pks.w = (uint_t)os[6] | ((uint_t)os[7] << 16);
    *(uint4*)(w1  + (size_t)gid * 8) = pk;
    *(uint4*)(w1s + (size_t)gid * 8) = pks;
  } else if (gid < 552960) {                // 576*10*64 wd frag-lanes
    int g2 = gid - 184320;
    int l = g2 & 63, tile = g2 >> 6;
    int nt = tile % 10, mt2 = tile / 10;
    int lm = l & 15, lgp = l >> 4;
    float vv[4];
#pragma unroll
    for (int r = 0; r < 4; ++r) {
      int krow = mt2 * 16 + lgp * 4 + r;
      int i = krow / CCAP, c = krow - i * CCAP;
      vv[r] = W[((size_t)(c * UU + nt) * 16 + lm) * 8 + i];
    }
    *(float4*)(wd + (size_t)g2 * 4) = make_float4(vv[0], vv[1], vv[2], vv[3]);
  } else if (gid < 564480) {
    lg[gid - 552960] = 0.f;
  }
}

// ---------------- x (fp32 row-major) -> xbf (bf16 row-major) ----------------
__global__ void k_xbf(const float* __restrict__ x, ushort_t* __restrict__ xbf) {
  int t = blockIdx.x * 256 + threadIdx.x;   // 294912 threads, 8 elems each
  const float4 a0 = *(const float4*)(x + (size_t)t * 8);
  const float4 a1 = *(const float4*)(x + (size_t)t * 8 + 4);
  uint4 pk;
  pk.x = (uint_t)f2bf(a0.x) | ((uint_t)f2bf(a0.y) << 16);
  pk.y = (uint_t)f2bf(a0.z) | ((uint_t)f2bf(a0.w) << 16);
  pk.z = (uint_t)f2bf(a1.x) | ((uint_t)f2bf(a1.y) << 16);
  pk.w = (uint_t)f2bf(a1.z) | ((uint_t)f2bf(a1.w) << 16);
  *(uint4*)(xbf + (size_t)t * 8) = pk;
}

// ---------------- transpose x[256][9216] -> xkbbf[9216][256] (bf16) ----------------
__global__ void k_xkb(const float* __restrict__ x, ushort_t* __restrict__ xkb) {
  __shared__ float tile[32][33];
  int k0 = blockIdx.x * 32, b0 = blockIdx.y * 32;
  int tx = threadIdx.x, ty = threadIdx.y;
#pragma unroll
  for (int r = 0; r < 32; r += 8)
    tile[ty + r][tx] = x[(size_t)(b0 + ty + r) * KK + k0 + tx];
  __syncthreads();
#pragma unroll
  for (int r = 0; r < 32; r += 8)
    xkb[(size_t)(k0 + ty + r) * BB + b0 + tx] = f2bf(tile[tx][ty + r]);
}

// ---------------- GEMM1 (pure MFMA): part[sp] = xbf * w1s ----------------
// grid (5 ntp, 48 sp), 256 thr = 4 waves; block = 256 rows x 32 cols, K-chunk 192.
__global__ __launch_bounds__(256) void k_gemm1(const ushort_t* __restrict__ xbf,
                                               const ushort_t* __restrict__ w1s,
                                               float* __restrict__ part) {
  int ntp = blockIdx.x;
  int sp  = blockIdx.y;
  int tid = threadIdx.x;
  int wv = tid >> 6, l = tid & 63;
  int lm = l & 15, lgp = l >> 4;
  f32x4 z = {0.f, 0.f, 0.f, 0.f};
  f32x4 acc[4][2];
#pragma unroll
  for (int q = 0; q < 4; ++q) { acc[q][0] = z; acc[q][1] = z; }
  for (int ktl = 0; ktl < KTL; ++ktl) {
    int kt = sp * KTL + ktl;
    bf16x8 af[4];
#pragma unroll
    for (int q = 0; q < 4; ++q)
      af[q] = *(const bf16x8*)(xbf + (size_t)(wv * 64 + q * 16 + lm) * KK + kt * 32 + lgp * 8);
    bf16x8 bfr[2];
#pragma unroll
    for (int nb = 0; nb < 2; ++nb)
      bfr[nb] = *(const bf16x8*)(w1s + ((size_t)kt * UU + ntp * 2 + nb) * 512 + (size_t)l * 8);
#pragma unroll
    for (int q = 0; q < 4; ++q)
#pragma unroll
      for (int nb = 0; nb < 2; ++nb)
        acc[q][nb] = __builtin_amdgcn_mfma_f32_16x16x32_bf16(af[q], bfr[nb], acc[q][nb], 0, 0, 0);
  }
  float* pb = part + (size_t)sp * POSN;
#pragma unroll
  for (int q = 0; q < 4; ++q)
#pragma unroll
    for (int nb = 0; nb < 2; ++nb)
#pragma unroll
      for (int r = 0; r < 4; ++r)
        pb[(size_t)(wv * 64 + q * 16 + lgp * 4 + r) * NN + ntp * 32 + nb * 16 + lm] = acc[q][nb][r];
}

// ---------------- reduce split-K + squash -> vbfT (or f32 out); zero ag ----------------
__global__ void k_reduce(const float* __restrict__ part, ushort_t* __restrict__ vbfT,
                         float* __restrict__ out, int last, float* __restrict__ ag) {
  int b = blockIdx.x, uo = threadIdx.x;   // 256 x 160
  if (b < 72) ag[b * NN + uo] = 0.f;      // 72*160 = 11520 = CCAP*UU
  float s = 0.f;
  for (int sp = 0; sp < KSPLIT; ++sp) s += part[(size_t)sp * POSN + b * NN + uo];
  float n2 = s * s;
#pragma unroll
  for (int off = 1; off < 16; off <<= 1) n2 += __shfl_xor(n2, off);
  float scale = n2 / ((1.f + n2) * sqrtf(n2));
  float vv = s * scale;
  if (last) out[b * NN + uo] = vv;
  else      vbfT[(size_t)uo * BB + b] = f2bf(vv);
}

// ---------------- GEMM2 (pure MFMA) + agreement epilogue -> atomic ag ----------------
// T[k][n] = sum_b xkb[k][b]*v[b][n]; ag[c][u] += sum_o wt[k][n]*T[k][n]
// grid (36 mb, 5 ntp), 256 thr = 4 waves; block = 256 k-rows, full b-reduction.
__global__ __launch_bounds__(256) void k_gemm2(const ushort_t* __restrict__ xkb,
                                               const ushort_t* __restrict__ vbfT,
                                               const float* __restrict__ wd,
                                               float* __restrict__ ag) {
  int mb = blockIdx.x;
  int ntp = blockIdx.y;
  int tid = threadIdx.x;
  int wv = tid >> 6, l = tid & 63;
  int lm = l & 15, lgp = l >> 4;
  f32x4 z = {0.f, 0.f, 0.f, 0.f};
  f32x4 acc[4][2];
#pragma unroll
  for (int q = 0; q < 4; ++q) { acc[q][0] = z; acc[q][1] = z; }
  for (int bt = 0; bt < 8; ++bt) {
    bf16x8 af[4];
#pragma unroll
    for (int q = 0; q < 4; ++q) {
      int mt2 = mb * 16 + wv * 4 + q;
      af[q] = *(const bf16x8*)(xkb + (size_t)(mt2 * 16 + lm) * BB + bt * 32 + lgp * 8);
    }
    bf16x8 bfr[2];
#pragma unroll
    for (int nb = 0; nb < 2; ++nb)
      bfr[nb] = *(const bf16x8*)(vbfT + (size_t)(ntp * 32 + nb * 16 + lm) * BB + bt * 32 + lgp * 8);
#pragma unroll
    for (int q = 0; q < 4; ++q)
#pragma unroll
      for (int nb = 0; nb < 2; ++nb)
        acc[q][nb] = __builtin_amdgcn_mfma_f32_16x16x32_bf16(af[q], bfr[nb], acc[q][nb], 0, 0, 0);
  }
  // epilogue: dot with W (D-layout pack), reduce over o (lm lanes), atomic into ag
#pragma unroll
  for (int q = 0; q < 4; ++q) {
    int mt2 = mb * 16 + wv * 4 + q;
#pragma unroll
    for (int nb = 0; nb < 2; ++nb) {
      int nt = ntp * 2 + nb;
      float4 wdv = *(const float4*)(wd + ((size_t)(mt2 * UU + nt) * 64 + l) * 4);
      float p0 = acc[q][nb][0] * wdv.x;
      float p1 = acc[q][nb][1] * wdv.y;
      float p2 = acc[q][nb][2] * wdv.z;
      float p3 = acc[q][nb][3] * wdv.w;
#pragma unroll
      for (int off = 1; off < 16; off <<= 1) {
        p0 += __shfl_xor(p0, off);
        p1 += __shfl_xor(p1, off);
        p2 += __shfl_xor(p2, off);
        p3 += __shfl_xor(p3, off);
      }
      if (lm == 0) {
        int krow = mt2 * 16 + lgp * 4;    // rows krow..krow+3 share i (16 | 1152)
        int c = krow % CCAP;
        atomicAdd(&ag[(c + 0) * UU + nt], p0);
        atomicAdd(&ag[(c + 1) * UU + nt], p1);
        atomicAdd(&ag[(c + 2) * UU + nt], p2);
        atomicAdd(&ag[(c + 3) * UU + nt], p3);
      }
    }
  }
}

// ---------------- finish: logits += ag/B, softmax -> cw ----------------
__global__ void k_finish(const float* __restrict__ ag, float* __restrict__ lg,
                         float* __restrict__ cw) {
  int c = blockIdx.x * 256 + threadIdx.x;
  if (c >= CCAP) return;
  float l[UU];
  float mx = -1e30f;
#pragma unroll
  for (int u = 0; u < UU; ++u) {
    float nl = lg[c * UU + u] + ag[c * UU + u] * (1.f / 256.f);
    lg[c * UU + u] = nl;
    l[u] = nl;
    mx = fmaxf(mx, nl);
  }
  float s = 0.f;
#pragma unroll
  for (int u = 0; u < UU; ++u) { l[u] = __expf(l[u] - mx); s += l[u]; }
  float inv = 1.f / s;
#pragma unroll
  for (int u = 0; u < UU; ++u) cw[c * UU + u] = l[u] * inv;
}

// ---------------- scale: w1s = bf16(cw * w1), fragment layout ----------------
__global__ void k_scale(const ushort_t* __restrict__ w1, const float* __restrict__ cw,
                        ushort_t* __restrict__ w1s) {
  int gid = blockIdx.x * 256 + threadIdx.x;   // 184320 frag-lanes
  int l = gid & 63, tile = gid >> 6;
  int nt = tile % 10, kt = tile / 10;
  int lgp = (l >> 4);
  int c0 = (kt * 32 + lgp * 8) % CCAP;        // run of 8 never crosses wrap (8 | 1152)
  uint4 raw = *(const uint4*)(w1 + (size_t)gid * 8);
  const float* cwp = cw + (size_t)c0 * UU + nt;
  uint4 pk;
  pk.x = (uint_t)f2bf(bf2f((ushort_t)(raw.x & 0xffff)) * cwp[0 * UU])
       | ((uint_t)f2bf(bf2f((ushort_t)(raw.x >> 16))   * cwp[1 * UU]) << 16);
  pk.y = (uint_t)f2bf(bf2f((ushort_t)(raw.y & 0xffff)) * cwp[2 * UU])
       | ((uint_t)f2bf(bf2f((ushort_t)(raw.y >> 16))   * cwp[3 * UU]) << 16);
  pk.z = (uint_t)f2bf(bf2f((ushort_t)(raw.z & 0xffff)) * cwp[4 * UU])
       | ((uint_t)f2bf(bf2f((ushort_t)(raw.z >> 16))   * cwp[5 * UU]) << 16);
  pk.w = (uint_t)f2bf(bf2f((ushort_t)(raw.w & 0xffff)) * cwp[6 * UU])
       | ((uint_t)f2bf(bf2f((ushort_t)(raw.w >> 16))   * cwp[7 * UU]) << 16);
  *(uint4*)(w1s + (size_t)gid * 8) = pk;
}

extern "C" void kernel_launch(void* const* d_in, const int* in_sizes, int n_in,
                              void* d_out, int out_size, void* d_ws, size_t ws_size,
                              hipStream_t stream) {
  const float* x = (const float*)d_in[0];
  const float* W = (const float*)d_in[1];
  float* out = (float*)d_out;
  char* ws = (char*)d_ws;

  const size_t off_w1   = 0;                     // 184320*16 = 2,949,120 B
  const size_t off_w1s  = off_w1 + 2949120;      // 2,949,120 B
  const size_t off_wd   = off_w1s + 2949120;     // 5,898,240 B
  const size_t off_xbf  = off_wd + 5898240;      // 2,359,296*2 = 4,718,592 B
  const size_t off_xkb  = off_xbf + 4718592;     // 4,718,592 B
  const size_t off_part = off_xkb + 4718592;     // 48*40960*4 = 7,864,320 B
  const size_t off_cw   = off_part + 7864320;    // 46,080 B
  const size_t off_lg   = off_cw + 46080;        // 46,080 B
  const size_t off_vbf  = off_lg + 46080;        // 160*256*2 = 81,920 B
  const size_t off_ag   = off_vbf + 81920;       // 46,080 B
  const size_t need     = off_ag + 46080;        // ~29.3 MB
  if (ws_size < need) return;  // output stays poisoned -> visible failure

  ushort_t* w1  = (ushort_t*)(ws + off_w1);
  ushort_t* w1s = (ushort_t*)(ws + off_w1s);
  float* wd     = (float*)(ws + off_wd);
  ushort_t* xbf = (ushort_t*)(ws + off_xbf);
  ushort_t* xkb = (ushort_t*)(ws + off_xkb);
  float* part   = (float*)(ws + off_part);
  float* cw     = (float*)(ws + off_cw);
  float* lg     = (float*)(ws + off_lg);
  ushort_t* vbfT= (ushort_t*)(ws + off_vbf);
  float* ag     = (float*)(ws + off_ag);

  k_prep<<<dim3(2205), dim3(256), 0, stream>>>(W, w1, w1s, wd, lg);
  k_xbf <<<dim3(1152), dim3(256), 0, stream>>>(x, xbf);
  k_xkb <<<dim3(KK / 32, BB / 32), dim3(32, 8), 0, stream>>>(x, xkb);

  for (int it = 0; it < 4; ++it) {
    k_gemm1 <<<dim3(5, KSPLIT), dim3(256), 0, stream>>>(xbf, w1s, part);
    k_reduce<<<dim3(BB), dim3(NN), 0, stream>>>(part, vbfT, out, (it == 3) ? 1 : 0, ag);
    if (it < 3) {
      k_gemm2 <<<dim3(36, 5), dim3(256), 0, stream>>>(xkb, vbfT, wd, ag);
      k_finish<<<dim3(5), dim3(256), 0, stream>>>(ag, lg, cw);
      k_scale <<<dim3(720), dim3(256), 0, stream>>>(w1, cw, w1s);
    }
  }
}